// Round 9
// baseline (207.492 us; speedup 1.0000x reference)
//
#include <hip/hip_runtime.h>

#define THREADS 512
#define RB      64     // rows per mainK block
#define RB2     64     // rows per finalize block
#define SCAP    64     // candidate-list / slot capacity (tau targets T~32: 4.6 sigma headroom)
#define KF      80     // compiled K (harness K=80)
#define K2      160    // 2*KF (C|D)

typedef float f4 __attribute__((ext_vector_type(4)));

__device__ __forceinline__ unsigned fmap(float x) {   // order-preserving float->uint
  unsigned u = __float_as_uint(x);
  return (u >> 31) ? ~u : (u | 0x80000000u);
}

// ================= mainK: list + assign + per-block compact record (plain stores, NO init needed) ===========
__global__ __launch_bounds__(THREADS)
void mainK(const float* __restrict__ S, const float* __restrict__ J,
           const float* __restrict__ C, const float* __restrict__ D,
           float tau,
           float* __restrict__ recSum, int* __restrict__ recSlot, int* __restrict__ recCnt,
           int* __restrict__ recNT,
           int* __restrict__ leader, int* __restrict__ lslot,
           int N, int K) {
  __shared__ int   listIdx[SCAP];
  __shared__ float listVal[SCAP];
  __shared__ int   wsum[8], wpre[8];
  __shared__ unsigned long long rowKey[RB];
  __shared__ int   rowSlot[RB];
  __shared__ float slotSum[SCAP * K2];   // 40 KB
  __shared__ int   slotCnt[SCAP];
  __shared__ int   invLoc[SCAP];         // loc -> slot
  __shared__ int   sT, sNT;
  __shared__ unsigned long long bkey;

  const int tid = threadIdx.x, lane = tid & 63, wv = tid >> 6;
  const int b = blockIdx.x, i0 = b * RB;

  // ---- A: block-invariant candidate list {j : S[j] >= tau}, index-ascending ----
  int T;
  {
    const bool vec4 = ((N & 3) == 0);
    int cl = 0;
    int a0 = 0, a1 = 0, j0 = 0, j1 = 0;
    if (vec4) {
      const int n4 = N >> 2;
      const int per4 = (n4 + THREADS - 1) / THREADS;
      a0 = tid * per4; a1 = min(n4, a0 + per4);
      for (int a = a0; a < a1; ++a) {
        f4 v = ((const f4*)S)[a];
        cl += (v.x >= tau) + (v.y >= tau) + (v.z >= tau) + (v.w >= tau);
      }
    } else {
      const int per = (N + THREADS - 1) / THREADS;
      j0 = tid * per; j1 = min(N, j0 + per);
      for (int j = j0; j < j1; ++j) cl += (S[j] >= tau);
    }
    int inc = cl;                          // two-level exclusive prefix over 512 counts
    for (int off = 1; off < 64; off <<= 1) {
      int o = __shfl_up(inc, off, 64);
      if (lane >= off) inc += o;
    }
    if (lane == 63) wsum[wv] = inc;
    __syncthreads();
    if (tid == 0) {
      int acc = 0;
      #pragma unroll
      for (int w = 0; w < 8; ++w) { wpre[w] = acc; acc += wsum[w]; }
      sT = acc;
    }
    __syncthreads();
    T = sT;
    if (T <= SCAP) {
      int pos = wpre[wv] + inc - cl;
      if (vec4) {
        for (int a = a0; a < a1; ++a) {
          f4 v = ((const f4*)S)[a];
          if (v.x >= tau) { listIdx[pos] = a*4+0; listVal[pos] = v.x; ++pos; }
          if (v.y >= tau) { listIdx[pos] = a*4+1; listVal[pos] = v.y; ++pos; }
          if (v.z >= tau) { listIdx[pos] = a*4+2; listVal[pos] = v.z; ++pos; }
          if (v.w >= tau) { listIdx[pos] = a*4+3; listVal[pos] = v.w; ++pos; }
        }
      } else {
        for (int j = j0; j < j1; ++j) {
          float v = S[j];
          if (v >= tau) { listIdx[pos] = j; listVal[pos] = v; ++pos; }
        }
      }
    }
  }
  const int ovf = (T > SCAP) | (K != KF);  // unconditional-correctness escape hatch

  // zero LDS accumulators + row state
  for (int idx = tid; idx < SCAP * K2; idx += THREADS) slotSum[idx] = 0.f;
  if (tid < SCAP) slotCnt[tid] = 0;
  if (tid < RB) { rowKey[tid] = 0ull; rowSlot[tid] = -1; }
  __syncthreads();

  // ---- B: leader assign, 8 threads/row over list slots; exact when a top-set nbr exists ----
  {
    const int r = tid & (RB - 1);          // 0..63 row
    const int g = tid >> 6;                // 0..7 candidate group
    const int i = i0 + r;
    if (!ovf && i < N) {
      unsigned long long lk = 0ull;
      for (int t = g; t < T; t += 8) {
        float v = J[(size_t)listIdx[t] * N + i];   // symmetric J: coalesced column read (diag=1 covers self)
        if (v > 0.5f) {
          unsigned long long key = ((unsigned long long)fmap(listVal[t]) << 32)
                                 | (unsigned)(0xFFFFFFFFu - (unsigned)t);
          if (key > lk) lk = key;                  // index-ascending slots: min slot == min index
        }
      }
      if (lk) atomicMax(&rowKey[r], lk);
    }
  }
  __syncthreads();
  if (tid < RB) {
    const int i = i0 + tid;
    if (i < N) {
      unsigned long long kk = ovf ? 0ull : rowKey[tid];
      if (kk != 0ull) {
        int slot = (int)(0xFFFFFFFFu - (unsigned)(kk & 0xFFFFFFFFull));
        rowSlot[tid] = slot;
        leader[i] = listIdx[slot];         // plain stores: kernel boundary syncs
        lslot[i]  = slot;
        atomicAdd(&slotCnt[slot], 1);
      } else {
        lslot[i] = -1;                     // brute below fills leader
      }
    }
  }
  __syncthreads();

  // ---- B': exact full-row argmax for unresolved rows (expected: none) ----
  for (int rr = 0; rr < RB; ++rr) {
    if (rowSlot[rr] != -1) continue;
    const int ii = i0 + rr;
    if (ii >= N) continue;
    if (tid == 0) bkey = 0ull;
    __syncthreads();
    unsigned long long bk = 0ull;
    for (int j = tid; j < N; j += THREADS) {
      float v = J[(size_t)ii * N + j];
      if (v > 0.5f || j == ii) {
        unsigned long long key = ((unsigned long long)fmap(S[j]) << 32)
                               | (unsigned)(0xFFFFFFFFu - (unsigned)j);
        if (key > bk) bk = key;
      }
    }
    if (bk) atomicMax(&bkey, bk);
    __syncthreads();
    if (tid == 0) leader[ii] = (int)(0xFFFFFFFFu - (unsigned)(bkey & 0xFFFFFFFFull));
    __syncthreads();
  }

  // ---- C: accumulate own rows into LDS slot table (slot-id indexed, no dedupe) ----
  for (int q = tid; q < RB * 40; q += THREADS) {      // 40 f4 per row (C:20|D:20)
    const int rr = q / 40, f = q - rr * 40;
    const int i = i0 + rr;
    if (i >= N) continue;
    const int s = rowSlot[rr];
    if (s < 0) continue;
    f4 v;
    if (f < 20) v = *(const f4*)(C + (size_t)i * KF + f * 4);
    else        v = *(const f4*)(D + (size_t)i * KF + (f - 20) * 4);
    float* dst = &slotSum[s * K2 + (f < 20 ? f * 4 : KF + (f - 20) * 4)];
    atomicAdd(dst + 0, v.x); atomicAdd(dst + 1, v.y);
    atomicAdd(dst + 2, v.z); atomicAdd(dst + 3, v.w);
  }
  __syncthreads();

  // ---- D: compact touched slots -> per-block record (plain stores, fully self-describing) ----
  if (tid < SCAP) {                         // exactly wave 0 (SCAP==64): full-wave ballot
    const bool flag = slotCnt[tid] > 0;
    unsigned long long m = __ballot(flag);
    int loc = (int)__popcll(m & ((1ull << lane) - 1ull));
    if (flag) {
      recSlot[b * SCAP + loc] = tid;
      recCnt [b * SCAP + loc] = slotCnt[tid];
      invLoc[loc] = tid;
    }
    if (tid == 0) { sNT = (int)__popcll(m); recNT[b] = (int)__popcll(m); }
  }
  __syncthreads();
  const int nT = sNT;
  for (int q = tid; q < nT * 40; q += THREADS) {
    const int loc = q / 40, f = q - loc * 40;
    const f4 v = *(const f4*)&slotSum[invLoc[loc] * K2 + f * 4];
    *(f4*)&recSum[((size_t)b * SCAP + loc) * K2 + f * 4] = v;
  }
}

// ================= finK: rebuild global segment sums from records, write rows =================
__global__ __launch_bounds__(THREADS)
void finK(const float* __restrict__ recSum, const int* __restrict__ recSlot,
          const int* __restrict__ recCnt, const int* __restrict__ recNT,
          const int* __restrict__ leader, const int* __restrict__ lslot,
          const float* __restrict__ C, const float* __restrict__ D,
          float* __restrict__ out, int N, int K, int nbm) {
  __shared__ float acc[SCAP * K2];   // 40 KB: full global slot sums
  __shared__ int   cntAcc[SCAP];
  __shared__ int   rslot[RB2];
  __shared__ float invS[SCAP];
  const int tid = threadIdx.x;
  const int g = blockIdx.x, r0 = g * RB2;
  const size_t NK = (size_t)N * K;

  for (int idx = tid; idx < SCAP * K2; idx += THREADS) acc[idx] = 0.f;
  if (tid < SCAP) cntAcc[tid] = 0;
  if (tid < RB2) {
    const int i = r0 + tid;
    rslot[tid] = (i < N) ? lslot[i] : -2;
  }
  __syncthreads();

  // gather ALL records into the global slot table (outer: record, inner: fully parallel)
  for (int b2 = 0; b2 < nbm; ++b2) {
    const int nt2 = recNT[b2];
    if (tid < nt2) atomicAdd(&cntAcc[recSlot[b2 * SCAP + tid]], recCnt[b2 * SCAP + tid]);
    for (int q = tid; q < nt2 * 40; q += THREADS) {
      const int t = q / 40, f = q - t * 40;
      const int s = recSlot[b2 * SCAP + t];              // L1-hot
      const f4 v = *(const f4*)&recSum[((size_t)b2 * SCAP + t) * K2 + f * 4];
      float* dst = &acc[s * K2 + f * 4];
      atomicAdd(dst + 0, v.x); atomicAdd(dst + 1, v.y);
      atomicAdd(dst + 2, v.z); atomicAdd(dst + 3, v.w);
    }
  }
  __syncthreads();
  if (tid < SCAP) {
    const int c = cntAcc[tid];
    invS[tid] = 1.0f / (float)(c > 0 ? c : 1);
  }
  __syncthreads();

  // write resolved rows (coalesced f4)
  for (int q = tid; q < RB2 * 40; q += THREADS) {
    const int rr = q / 40, f = q - rr * 40;
    const int i = r0 + rr;
    if (i >= N) continue;
    const int s = rslot[rr];
    if (s < 0) continue;
    const float iv = invS[s];
    const f4 v0 = *(const f4*)&acc[s * K2 + (f < 20 ? f * 4 : KF + (f - 20) * 4)];
    f4 v = { v0.x * iv, v0.y * iv, v0.z * iv, v0.w * iv };
    const size_t off = (f < 20) ? ((size_t)i * KF + f * 4)
                                : (NK + (size_t)i * KF + (f - 20) * 4);
    *(f4*)(out + off) = v;
  }

  // fallback rows: exact leader-scan mean (expected: none; any K)
  for (int rr = 0; rr < RB2; ++rr) {
    if (rslot[rr] != -1) continue;
    const int ii = r0 + rr;
    const int m = leader[ii];
    for (int k = tid; k < K; k += THREADS) {
      float sc = 0.f, sd = 0.f; int cc = 0;
      for (int y = 0; y < N; ++y)
        if (leader[y] == m) { sc += C[(size_t)y * K + k]; sd += D[(size_t)y * K + k]; ++cc; }
      const float iv = 1.0f / (float)(cc > 0 ? cc : 1);
      out[(size_t)ii * K + k] = sc * iv;
      out[NK + (size_t)ii * K + k] = sd * iv;
    }
  }
}

extern "C" void kernel_launch(void* const* d_in, const int* in_sizes, int n_in,
                              void* d_out, int out_size, void* d_ws, size_t ws_size,
                              hipStream_t stream) {
  (void)n_in; (void)out_size; (void)ws_size;
  const float* S = (const float*)d_in[0];
  const float* J = (const float*)d_in[1];
  const float* C = (const float*)d_in[2];
  const float* D = (const float*)d_in[3];
  float* out = (float*)d_out;
  const int N = in_sizes[0];
  const int K = in_sizes[2] / N;
  const int nbm = (N + RB - 1) / RB;       // 128 mainK blocks for N=8192

  // ws layout (NO memset — every byte read is written this call):
  // recSum[nbm][SCAP][K2] | recSlot[nbm][SCAP] | recCnt[nbm][SCAP] | recNT[nbm] | leader[N] | lslot[N]
  float* recSum  = (float*)d_ws;
  int*   recSlot = (int*)(recSum + (size_t)nbm * SCAP * K2);
  int*   recCnt  = recSlot + (size_t)nbm * SCAP;
  int*   recNT   = recCnt + (size_t)nbm * SCAP;
  int*   leader  = recNT + nbm;
  int*   lslot   = leader + N;

  const float tau = 1.0f - 32.0f / (float)N;   // targets E[T]=32; any tau is correct
  mainK<<<nbm, THREADS, 0, stream>>>(S, J, C, D, tau, recSum, recSlot, recCnt, recNT,
                                     leader, lslot, N, K);
  const int nfb = (N + RB2 - 1) / RB2;         // 128 finalize blocks
  finK<<<nfb, THREADS, 0, stream>>>(recSum, recSlot, recCnt, recNT, leader, lslot,
                                    C, D, out, N, K, nbm);
}

// Round 10
// 47.273 us; speedup vs baseline: 4.3892x; 4.3892x over previous
//
#include <hip/hip_runtime.h>

#define THREADS 256
#define RB      16       // rows per mainK block
#define LCAP    128      // candidate-list capacity
#define KF      80       // compiled K (harness K=80)
#define K2      160      // 2*KF (C|D)
#define NPART   8        // partitioned partials (b&7 ~ XCD id)
#define MAXRES  512      // co-resident blocks: 2/CU x 256 CU (enforced by __launch_bounds__)
#define ZWORDS  (NPART * LCAP * K2 + LCAP)   // slotPart + slotCount = 163968 words
#define MAGIC   0x5EED5EEDu

typedef float f4 __attribute__((ext_vector_type(4)));

__device__ __forceinline__ unsigned fmap(float x) {   // order-preserving float->uint
  unsigned u = __float_as_uint(x);
  return (u >> 31) ? ~u : (u | 0x80000000u);
}

// ================= mainK: self-zero + list + assign + scatter + flush =================
__global__ __launch_bounds__(THREADS, 2)
void mainK(const float* __restrict__ S, const float* __restrict__ J,
           const float* __restrict__ C, const float* __restrict__ D,
           float tau,
           float* __restrict__ slotPart, int* __restrict__ slotCount,
           unsigned* __restrict__ zeroFlag,
           int* __restrict__ leader, int* __restrict__ lslot,
           int N, int K, int precleared) {
  __shared__ int   listIdx[LCAP];
  __shared__ float listVal[LCAP];
  __shared__ int   cnts[THREADS];
  __shared__ unsigned long long rowKey[RB];
  __shared__ int   rowSlot[RB];
  __shared__ int   rowLocal[RB];
  __shared__ int   touchSlot[RB];
  __shared__ int   touchCnt[RB];
  __shared__ int   unresR[RB];
  __shared__ int   sT, sNT, sNU;
  __shared__ unsigned long long bkey;
  __shared__ float slab[RB * K2];          // 10.2 KB

  const int tid = threadIdx.x;
  const int b   = blockIdx.x;
  const int i0  = b * RB;
  const int nblk = gridDim.x;

  // ---- Z: zero own exclusive slice of slotPart|slotCount via MALL-visible atomic stores ----
  if (!precleared) {
    const int per = (ZWORDS + nblk - 1) / nblk;
    const int z0 = b * per, z1 = min(ZWORDS, z0 + per);
    for (int idx = z0 + tid; idx < z1; idx += THREADS)
      __hip_atomic_store(&slotPart[idx], 0.0f, __ATOMIC_RELAXED, __HIP_MEMORY_SCOPE_AGENT);
    __syncthreads();                        // drains vmcnt: all zero-stores at MALL
    if (tid == 0)
      __hip_atomic_store(&zeroFlag[b], MAGIC, __ATOMIC_RELEASE, __HIP_MEMORY_SCOPE_AGENT);
  }

  // ---- A: block-invariant candidate list {j : S[j] >= tau}, index-ascending ----
  int T;
  {
    const bool vec4 = ((N & 3) == 0);
    int cl = 0;
    if (vec4) {
      const int n4 = N >> 2;
      const int per4 = (n4 + THREADS - 1) / THREADS;
      const int a0 = tid * per4, a1 = min(n4, a0 + per4);
      for (int a = a0; a < a1; ++a) {
        f4 v = ((const f4*)S)[a];
        cl += (v.x >= tau) + (v.y >= tau) + (v.z >= tau) + (v.w >= tau);
      }
    } else {
      const int per = (N + THREADS - 1) / THREADS;
      const int j0 = tid * per, j1 = min(N, j0 + per);
      for (int j = j0; j < j1; ++j) cl += (S[j] >= tau);
    }
    cnts[tid] = cl;
    if (tid == 0) { sNU = 0; sNT = 0; }
    __syncthreads();
    if (tid < 64) {                        // wave-0 exclusive prefix over 256 counts
      const int base = tid * 4;
      int a0 = cnts[base], a1 = cnts[base+1], a2 = cnts[base+2], a3 = cnts[base+3];
      int s = a0 + a1 + a2 + a3;
      int inc = s;
      for (int off = 1; off < 64; off <<= 1) { int o = __shfl_up(inc, off, 64); if (tid >= off) inc += o; }
      int exc = inc - s;
      cnts[base] = exc; cnts[base+1] = exc + a0;
      cnts[base+2] = exc + a0 + a1; cnts[base+3] = exc + a0 + a1 + a2;
      if (tid == 63) sT = inc;
    }
    __syncthreads();
    T = sT;
    if (T <= LCAP) {
      int pos = cnts[tid];
      if (vec4) {
        const int n4 = N >> 2;
        const int per4 = (n4 + THREADS - 1) / THREADS;
        const int a0 = tid * per4, a1 = min(n4, a0 + per4);
        for (int a = a0; a < a1; ++a) {
          f4 v = ((const f4*)S)[a];
          if (v.x >= tau) { listIdx[pos] = a*4+0; listVal[pos] = v.x; ++pos; }
          if (v.y >= tau) { listIdx[pos] = a*4+1; listVal[pos] = v.y; ++pos; }
          if (v.z >= tau) { listIdx[pos] = a*4+2; listVal[pos] = v.z; ++pos; }
          if (v.w >= tau) { listIdx[pos] = a*4+3; listVal[pos] = v.w; ++pos; }
        }
      } else {
        const int per = (N + THREADS - 1) / THREADS;
        const int j0 = tid * per, j1 = min(N, j0 + per);
        for (int j = j0; j < j1; ++j) {
          float v = S[j];
          if (v >= tau) { listIdx[pos] = j; listVal[pos] = v; ++pos; }
        }
      }
    }
  }
  const int ovf = (T > LCAP) | (K != KF);  // unconditional-correctness escape hatch
  if (tid < RB) { rowKey[tid] = 0ull; rowSlot[tid] = -1; rowLocal[tid] = -1; }
  __syncthreads();

  // ---- B: leader assign, 16 threads/row over list slots; exact when a top-set nbr exists ----
  {
    const int r = tid & (RB - 1);
    const int g = tid >> 4;
    const int i = i0 + r;
    if (!ovf && i < N) {
      unsigned long long lk = 0ull;
      for (int t = g; t < T; t += 16) {
        const int cand = listIdx[t];
        float v = J[(size_t)cand * N + i];   // symmetric J: coalesced column read (diag=1 covers self)
        if (v > 0.5f || cand == i) {
          unsigned long long key = ((unsigned long long)fmap(listVal[t]) << 32)
                                 | (unsigned)(0xFFFFFFFFu - (unsigned)t);
          if (key > lk) lk = key;            // index-ascending slots: min slot == min index
        }
      }
      if (lk) atomicMax(&rowKey[r], lk);
    }
  }
  __syncthreads();
  if (tid < RB) {
    const int i = i0 + tid;
    if (i < N) {
      unsigned long long k = ovf ? 0ull : rowKey[tid];
      if (k != 0ull) {
        int slot = (int)(0xFFFFFFFFu - (unsigned)(k & 0xFFFFFFFFull));
        rowSlot[tid] = slot;
        leader[i] = listIdx[slot];           // plain store: kernel boundary syncs
        lslot[i]  = slot;
      } else {
        lslot[i] = -1;
        int u = atomicAdd(&sNU, 1);
        unresR[u] = tid;
      }
    }
  }
  __syncthreads();

  // ---- B': exact full-row argmax for unresolved rows (expected: none) ----
  const int nu = sNU;
  for (int u = 0; u < nu; ++u) {
    const int rr = unresR[u]; const int ii = i0 + rr;
    if (tid == 0) bkey = 0ull;
    __syncthreads();
    unsigned long long bk = 0ull;
    for (int j = tid; j < N; j += THREADS) {
      float v = J[(size_t)ii * N + j];
      if (v > 0.5f || j == ii) {
        unsigned long long key = ((unsigned long long)fmap(S[j]) << 32)
                               | (unsigned)(0xFFFFFFFFu - (unsigned)j);
        if (key > bk) bk = key;
      }
    }
    if (bk) atomicMax(&bkey, bk);
    __syncthreads();
    if (tid == 0) leader[ii] = (int)(0xFFFFFFFFu - (unsigned)(bkey & 0xFFFFFFFFull));
    __syncthreads();
  }

  // ---- touch map: wave-parallel dedupe of this block's slots (<=16 distinct) ----
  if (tid < RB) {
    int s = rowSlot[tid];
    int first = tid;
    if (s >= 0) { first = 0; while (rowSlot[first] != s) ++first; }
    unsigned long long m = __ballot(s >= 0 && first == tid);
    if (s >= 0) {
      int loc = (int)__popcll(m & ((1ull << first) - 1ull));
      rowLocal[tid] = loc;
      if (first == tid) {
        int cnt = 0;
        for (int rr = 0; rr < RB; ++rr) cnt += (rowSlot[rr] == s);
        touchSlot[loc] = s; touchCnt[loc] = cnt;
      }
    }
    if (tid == 0) sNT = (int)__popcll(m);
  }
  __syncthreads();
  const int nT = sNT;

  // ---- C: per-ROW slab, plain f4 LDS stores ----
  for (int q = tid; q < RB * 40; q += THREADS) {      // 40 f4 per row (C:20|D:20)
    const int rr = q / 40, f = q - rr * 40;
    const int i = i0 + rr;
    if (i >= N || rowLocal[rr] < 0) continue;
    f4 v;
    if (f < 20) v = *(const f4*)(C + (size_t)i * KF + f * 4);
    else        v = *(const f4*)(D + (size_t)i * KF + (f - 20) * 4);
    *(f4*)&slab[rr * K2 + (f < 20 ? f * 4 : KF + (f - 20) * 4)] = v;
  }
  __syncthreads();

  // ---- W: wait until ALL blocks finished zeroing (expected: already done ~10us ago) ----
  if (!precleared) {
    for (int f = tid; f < nblk; f += THREADS) {
      while (__hip_atomic_load(&zeroFlag[f], __ATOMIC_RELAXED, __HIP_MEMORY_SCOPE_AGENT) != MAGIC)
        __builtin_amdgcn_s_sleep(32);
    }
    __syncthreads();
  }

  // ---- D: flush counts + per-slot row-sums into partition b&7 ----
  if (tid < nT) atomicAdd(&slotCount[touchSlot[tid]], touchCnt[tid]);
  {
    const int p = b & (NPART - 1);
    for (int q = tid; q < nT * 40; q += THREADS) {
      const int loc = q / 40, f4i = q - loc * 40;
      float ax = 0.f, ay = 0.f, az = 0.f, aw = 0.f;
      for (int rr = 0; rr < RB; ++rr) {
        if (rowLocal[rr] == loc) {
          const f4 v = *(const f4*)&slab[rr * K2 + f4i * 4];
          ax += v.x; ay += v.y; az += v.z; aw += v.w;
        }
      }
      float* dst = slotPart + ((size_t)p * LCAP + touchSlot[loc]) * K2 + f4i * 4;
      atomicAdd(dst + 0, ax); atomicAdd(dst + 1, ay);
      atomicAdd(dst + 2, az); atomicAdd(dst + 3, aw);
    }
  }
}

// ================= finalizeK (K%4==0): out[i,k] = sum[leader]/count =================
__global__ __launch_bounds__(THREADS)
void finalizeK(const float* __restrict__ slotPart, const int* __restrict__ slotCount,
               unsigned* __restrict__ zeroFlag,
               const int* __restrict__ leader, const int* __restrict__ lslot,
               const float* __restrict__ C, const float* __restrict__ D,
               float* __restrict__ out, int N, int K, int nblkMain, int precleared) {
  if (!precleared && blockIdx.x == 0) {     // reset flags for next call (kernel boundary orders)
    for (int f = threadIdx.x; f < nblkMain; f += THREADS)
      __hip_atomic_store(&zeroFlag[f], 0u, __ATOMIC_RELAXED, __HIP_MEMORY_SCOPE_AGENT);
  }
  const int NK4 = N * K / 4;
  int idx = blockIdx.x * THREADS + threadIdx.x;
  if (idx >= 2 * NK4) return;
  const bool isD = (idx >= NK4);
  const int rem = isD ? idx - NK4 : idx;
  const int kq = K / 4;
  const int i  = rem / kq;
  const int k0 = (rem - i * kq) * 4;
  const int slot = lslot[i];
  f4 acc;
  if (slot >= 0) {
    float ax = 0.f, ay = 0.f, az = 0.f, aw = 0.f;
    const float* base = slotPart + (size_t)slot * K2 + (isD ? KF : 0) + k0;
    #pragma unroll
    for (int p = 0; p < NPART; ++p) {
      const f4 v = *(const f4*)(base + (size_t)p * LCAP * K2);
      ax += v.x; ay += v.y; az += v.z; aw += v.w;
    }
    const int c = slotCount[slot];
    const float inv = 1.0f / (float)(c > 0 ? c : 1);
    acc = (f4){ ax * inv, ay * inv, az * inv, aw * inv };
  } else {
    // exact leader-scan mean (expected never; correctness escape hatch)
    const int m = leader[i];
    const float* src = isD ? D : C;
    float s0 = 0.f, s1 = 0.f, s2 = 0.f, s3 = 0.f; int cc = 0;
    for (int y = 0; y < N; ++y) {
      if (leader[y] == m) {
        const float* r = src + (size_t)y * K + k0;
        s0 += r[0]; s1 += r[1]; s2 += r[2]; s3 += r[3]; ++cc;
      }
    }
    const float inv = 1.0f / (float)(cc > 0 ? cc : 1);
    acc = (f4){ s0 * inv, s1 * inv, s2 * inv, s3 * inv };
  }
  ((f4*)out)[idx] = acc;
}

// ================= scalar finalize for K % 4 != 0 (rare shape; correctness path) =================
__global__ __launch_bounds__(THREADS)
void finalizeScalarK(const float* __restrict__ slotPart, const int* __restrict__ slotCount,
                     unsigned* __restrict__ zeroFlag,
                     const int* __restrict__ leader, const int* __restrict__ lslot,
                     const float* __restrict__ C, const float* __restrict__ D,
                     float* __restrict__ out, int N, int K, int nblkMain, int precleared) {
  if (!precleared && blockIdx.x == 0) {
    for (int f = threadIdx.x; f < nblkMain; f += THREADS)
      __hip_atomic_store(&zeroFlag[f], 0u, __ATOMIC_RELAXED, __HIP_MEMORY_SCOPE_AGENT);
  }
  const int NK = N * K;
  int idx = blockIdx.x * THREADS + threadIdx.x;
  if (idx >= 2 * NK) return;
  const bool isD = (idx >= NK);
  const int rem = isD ? idx - NK : idx;
  const int i = rem / K, k = rem - i * K;
  const int m = leader[i];
  const float* src = isD ? D : C;
  float s = 0.f; int cc = 0;
  for (int y = 0; y < N; ++y)
    if (leader[y] == m) { s += src[(size_t)y * K + k]; ++cc; }
  out[idx] = s / (float)(cc > 0 ? cc : 1);
}

extern "C" void kernel_launch(void* const* d_in, const int* in_sizes, int n_in,
                              void* d_out, int out_size, void* d_ws, size_t ws_size,
                              hipStream_t stream) {
  (void)n_in; (void)out_size; (void)ws_size;
  const float* S = (const float*)d_in[0];
  const float* J = (const float*)d_in[1];
  const float* C = (const float*)d_in[2];
  const float* D = (const float*)d_in[3];
  float* out = (float*)d_out;
  const int N = in_sizes[0];
  const int K = in_sizes[2] / N;
  const int NK = N * K;

  // ws layout: slotPart[NPART][LCAP][K2] | slotCount[LCAP] | zeroFlag[512] | leader[N] | lslot[N]
  float*    slotPart  = (float*)d_ws;
  int*      slotCount = (int*)(slotPart + (size_t)NPART * LCAP * K2);
  unsigned* zeroFlag  = (unsigned*)(slotCount + LCAP);
  int*      leader    = (int*)(zeroFlag + MAXRES);
  int*      lslot     = leader + N;

  const int nblk = (N + RB - 1) / RB;
  const int precleared = (nblk > MAXRES) ? 1 : 0;   // co-residency cap for self-zero handshake
  if (precleared)
    (void)hipMemsetAsync(d_ws, 0, (size_t)ZWORDS * sizeof(float), stream);

  const float tau = 1.0f - 48.0f / (float)N;   // targets E[T]=48; any tau is correct
  mainK<<<nblk, THREADS, 0, stream>>>(S, J, C, D, tau, slotPart, slotCount, zeroFlag,
                                      leader, lslot, N, K, precleared);
  if ((K & 3) == 0) {
    finalizeK<<<(2 * (NK / 4) + THREADS - 1) / THREADS, THREADS, 0, stream>>>(
        slotPart, slotCount, zeroFlag, leader, lslot, C, D, out, N, K, nblk, precleared);
  } else {
    finalizeScalarK<<<(2 * NK + THREADS - 1) / THREADS, THREADS, 0, stream>>>(
        slotPart, slotCount, zeroFlag, leader, lslot, C, D, out, N, K, nblk, precleared);
  }
}